// Round 2
// baseline (1375.377 us; speedup 1.0000x reference)
//
#include <hip/hip_runtime.h>
#include <stdint.h>
#include <stddef.h>

typedef __attribute__((ext_vector_type(8))) short short8;
typedef __attribute__((ext_vector_type(4))) float f32x4;
typedef unsigned short u16;

#define B_ 4
#define S_ 2048
#define H_ 2048
#define I_ 5504
#define M_ 8192  // B*S

__device__ __forceinline__ u16 f2bf(float f) {
  uint32_t u = __float_as_uint(f);
  u += 0x7fff + ((u >> 16) & 1);  // round-to-nearest-even
  return (u16)(u >> 16);
}

#define GLOAD_LDS16(src, dst)                                                            \
  __builtin_amdgcn_global_load_lds((const __attribute__((address_space(1))) void*)(src), \
                                   (__attribute__((address_space(3))) void*)(dst), 16, 0, 0)

// ---- fp32 -> bf16 convert (vectorized) ----
__global__ __launch_bounds__(256) void cvt_f32_bf16(const float* __restrict__ in,
                                                    u16* __restrict__ out, int n4) {
  int i = blockIdx.x * 256 + threadIdx.x;
  if (i < n4) {
    float4 v = ((const float4*)in)[i];
    ushort4 o;
    o.x = f2bf(v.x); o.y = f2bf(v.y); o.z = f2bf(v.z); o.w = f2bf(v.w);
    ((ushort4*)out)[i] = o;
  }
}

// ---- build interleaved W_cat [11008, 2048]: 32-row groups = 16 Wg rows then 16 Wu rows ----
__global__ __launch_bounds__(256) void cvt_wcat(const float* __restrict__ wg,
                                                const float* __restrict__ wu,
                                                u16* __restrict__ wcat) {
  const int i = blockIdx.x * 256 + threadIdx.x;  // float4 index
  const int f = i * 4;
  const int r = f >> 11;   // wcat row (2048 cols per row)
  const int c = f & 2047;
  const int srcrow = (r >> 5) * 16 + (r & 15);
  const float* src = (((r >> 4) & 1) ? wu : wg) + (size_t)srcrow * 2048 + c;
  float4 v = *(const float4*)src;
  ushort4 o;
  o.x = f2bf(v.x); o.y = f2bf(v.y); o.z = f2bf(v.z); o.w = f2bf(v.w);
  *(ushort4*)(wcat + (size_t)r * 2048 + c) = o;
}

// Stage one 16 KiB half-tile (256 rows x 32 k, bf16) into a linear LDS slot.
// LDS dest is wave-uniform base + lane*16 (HW); global source is per-lane and
// carries the inverse chunk-swizzle so the ds_read side can XOR the same way.
__device__ __forceinline__ void stage_half(const u16* __restrict__ mbase, int ld, int k0,
                                           char* slot, int tid) {
#pragma unroll
  for (int i = 0; i < 2; ++i) {
    const int f = tid * 16 + i * 8192;           // this lane's byte position in the slot
    const int row = f >> 6;                      // 64 B per row (32 bf16)
    const int cl = (f >> 4) & 3;                 // 16B chunk within row
    const int col = k0 + 8 * (cl ^ ((row >> 1) & 3));  // inverse swizzle on source
    GLOAD_LDS16(mbase + (size_t)row * ld + col,
                slot + ((tid >> 6) * 1024 + i * 8192));
  }
}

#define BAR1 asm volatile("s_barrier" ::: "memory")
#define ENDP                                                       \
  {                                                                \
    asm volatile("s_waitcnt lgkmcnt(0)" ::: "memory");             \
    asm volatile("s_barrier" ::: "memory");                        \
  }

#define MM(Aop, Bop, N0)                                                                    \
  {                                                                                         \
    __builtin_amdgcn_s_setprio(1);                                                          \
    _Pragma("unroll") for (int m = 0; m < 8; ++m) {                                         \
      acc[m][N0] = __builtin_amdgcn_mfma_f32_16x16x32_bf16(Aop[m], Bop[N0], acc[m][N0], 0, 0, 0); \
      acc[m][N0 + 1] =                                                                      \
          __builtin_amdgcn_mfma_f32_16x16x32_bf16(Aop[m], Bop[N0 + 1], acc[m][N0 + 1], 0, 0, 0);  \
    }                                                                                       \
    __builtin_amdgcn_s_setprio(0);                                                          \
  }

// 256x256 tile, BK=64, 8 waves (2M x 4N), 8-phase pipelined K-loop with counted vmcnt.
// EPI=0: plain fp32 C write (down proj). EPI=1: SwiGLU epilogue (gate/up interleaved in B).
template <int EPI>
__global__ __launch_bounds__(512, 1) void gemm8(const u16* __restrict__ A,
                                                const u16* __restrict__ Bm, const int K,
                                                const int NT, float* __restrict__ outf,
                                                u16* __restrict__ inter, float* __restrict__ s) {
  __shared__ __align__(16) char lds_raw[131072 + 512];

  const int nwg = gridDim.x;        // divisible by 8
  const int cpx = nwg >> 3;
  const int swz = (blockIdx.x & 7) * cpx + (blockIdx.x >> 3);
  const int mt = swz / NT;
  const int nt = swz % NT;

  const int tid = threadIdx.x;
  const int lane = tid & 63;
  const int wid = tid >> 6;
  const int wr = wid >> 2;  // 0..1  (M half)
  const int wc = wid & 3;   // 0..3  (N quarter)
  const int l15 = lane & 15;

  if (tid < 128) ((float*)(lds_raw + 131072))[tid] = 0.f;

  // per-lane ds_read byte offsets (swizzled chunk): chunk = (lane>>4) ^ ((l15>>1)&3)
  const int chunkx = (l15 >> 1) & 3;
  const int aoff = (wr * 128 + l15) * 64 + (((lane >> 4) ^ chunkx) << 4);
  const int boff = (wc * 64 + l15) * 64 + (((lane >> 4) ^ chunkx) << 4);

  const u16* Abase = A + (size_t)(mt * 256) * K;
  const u16* Bbase = Bm + (size_t)(nt * 256) * K;

// slot q: 0=A_k0 1=A_k1 2=B_k0 3=B_k1 ; buffer = tile&1
#define STG(v, q)                                                          \
  stage_half((q) < 2 ? Abase : Bbase, K, (v) * 64 + ((q) & 1) * 32,        \
             lds_raw + (((v) & 1) * 65536 + (q) * 16384), tid)
#define RDA(dst, bank, ks)                                                            \
  _Pragma("unroll") for (int m = 0; m < 8; ++m) dst[m] =                              \
      *(const short8*)(lds_raw + (bank) * 65536 + (ks) * 16384 + aoff + m * 1024);
#define RDB(dst, bank, ks)                                                            \
  _Pragma("unroll") for (int n = 0; n < 4; ++n) dst[n] =                              \
      *(const short8*)(lds_raw + (bank) * 65536 + 32768 + (ks) * 16384 + boff + n * 1024);

  f32x4 acc[8][4] = {};
  short8 a0[8], a1A[8], a1B[8];
  short8 b0[4], b1A[4], b1B[4];

  const int T = K >> 6;  // K-tiles (even: 32 or 86)

  // ---- prologue: tile0 all 4 halves + tile1 A0,A1,B0; wait tile0 landed (<=6 pending)
  STG(0, 0); STG(0, 1); STG(0, 2); STG(0, 3);
  STG(1, 0); STG(1, 1); STG(1, 2);
  asm volatile("s_waitcnt vmcnt(6)" ::: "memory");
  BAR1;

#pragma unroll 1
  for (int t = 0; t < T; t += 2) {
    const bool lastpair = (t == T - 2);
    // ================= tile t (even buffer, ks1 regs -> bank A) =================
    // P0: read A_k0(t); stage B1(t+1); MFMA = ks1 of tile t-1 (bank B), n 0-1
    RDA(a0, 0, 0);
    STG(t + 1, 3);
    BAR1;
    if (t > 0) MM(a1B, b1B, 0);
    ENDP;
    // P1: read A_k1(t); stage A0(t+2); MFMA ks1(t-1) n 2-3
    RDA(a1A, 0, 1);
    if (!lastpair) STG(t + 2, 0);
    BAR1;
    if (t > 0) MM(a1B, b1B, 2);
    ENDP;
    // P2: read B_k0(t); stage A1(t+2); MFMA ks0(t) n 0-1
    RDB(b0, 0, 0);
    if (!lastpair) STG(t + 2, 1);
    BAR1;
    MM(a0, b0, 0);
    ENDP;
    // P3: read B_k1(t); stage B0(t+2); MFMA ks0(t) n 2-3; tile-boundary vmcnt
    RDB(b1A, 0, 1);
    if (!lastpair) STG(t + 2, 2);
    BAR1;
    MM(a0, b0, 2);
    if (lastpair)
      asm volatile("s_waitcnt vmcnt(0) lgkmcnt(0)" ::: "memory");
    else
      asm volatile("s_waitcnt vmcnt(6) lgkmcnt(0)" ::: "memory");
    BAR1;
    // ================= tile t+1 (odd buffer, ks1 regs -> bank B) =================
    // P0: read A_k0(t+1); stage B1(t+2); MFMA ks1(t) (bank A) n 0-1
    RDA(a0, 1, 0);
    if (!lastpair) STG(t + 2, 3);
    BAR1;
    MM(a1A, b1A, 0);
    ENDP;
    // P1: read A_k1(t+1); stage A0(t+3); MFMA ks1(t) n 2-3
    RDA(a1B, 1, 1);
    if (!lastpair) STG(t + 3, 0);
    BAR1;
    MM(a1A, b1A, 2);
    ENDP;
    // P2: read B_k0(t+1); stage A1(t+3); MFMA ks0(t+1) n 0-1
    RDB(b0, 1, 0);
    if (!lastpair) STG(t + 3, 1);
    BAR1;
    MM(a0, b0, 0);
    ENDP;
    // P3: read B_k1(t+1); stage B0(t+3); MFMA ks0(t+1) n 2-3
    RDB(b1B, 1, 1);
    if (!lastpair) STG(t + 3, 2);
    BAR1;
    MM(a0, b0, 2);
    if (!lastpair) asm volatile("s_waitcnt vmcnt(6) lgkmcnt(0)" ::: "memory");
    else asm volatile("s_waitcnt lgkmcnt(0)" ::: "memory");
    BAR1;
  }
  // epilogue MFMAs: ks1 of last (odd) tile, bank B
  MM(a1B, b1B, 0);
  MM(a1B, b1B, 2);

  // C/D frag mapping: col = lane&15, row = (lane>>4)*4 + j
  const int r0 = mt * 256 + wr * 128 + (lane >> 4) * 4;
  if constexpr (EPI == 0) {
    const int c0 = nt * 256 + wc * 64 + l15;
#pragma unroll
    for (int m = 0; m < 8; ++m)
#pragma unroll
      for (int n = 0; n < 4; ++n)
#pragma unroll
        for (int j = 0; j < 4; ++j)
          outf[(size_t)(r0 + m * 16 + j) * 2048 + (c0 + n * 16)] = acc[m][n][j];
  } else {
    // n pairs (0,1)=(gate,up) cols c0..c0+15 ; (2,3)=(gate,up) cols c0+16..c0+31
    float* s_tile = (float*)(lds_raw + 131072);
    const int c0 = nt * 128 + wc * 32 + l15;
    float sp0 = 0.f, sp1 = 0.f;
#pragma unroll
    for (int m = 0; m < 8; ++m) {
#pragma unroll
      for (int j = 0; j < 4; ++j) {
        {
          const float g = acc[m][0][j], u = acc[m][1][j];
          const float v = (g / (1.f + __expf(-g))) * u;
          sp0 += v * v;
          inter[(size_t)(r0 + m * 16 + j) * I_ + c0] = f2bf(v);
        }
        {
          const float g = acc[m][2][j], u = acc[m][3][j];
          const float v = (g / (1.f + __expf(-g))) * u;
          sp1 += v * v;
          inter[(size_t)(r0 + m * 16 + j) * I_ + (c0 + 16)] = f2bf(v);
        }
      }
    }
    atomicAdd(&s_tile[wc * 32 + l15], sp0);
    atomicAdd(&s_tile[wc * 32 + 16 + l15], sp1);
    __syncthreads();
    if (tid < 128) atomicAdd(&s[(mt >> 3) * I_ + nt * 128 + tid], s_tile[tid]);
  }
#undef STG
#undef RDA
#undef RDB
}

// ---- row_sq (fp32 w_up) + impacts ----
__global__ __launch_bounds__(256) void rowsq_impacts(const float* __restrict__ wu,
                                                     const float* __restrict__ s,
                                                     float* __restrict__ imp) {
  const int i = blockIdx.x;
  const int tid = threadIdx.x;
  const float4* row = (const float4*)(wu + (size_t)i * H_);
  float acc = 0.f;
#pragma unroll
  for (int t = 0; t < 2; ++t) {
    float4 v = row[tid + t * 256];
    acc += v.x * v.x + v.y * v.y + v.z * v.z + v.w * v.w;
  }
#pragma unroll
  for (int off = 32; off > 0; off >>= 1) acc += __shfl_down(acc, off, 64);
  __shared__ float wsum[4];
  if ((tid & 63) == 0) wsum[tid >> 6] = acc;
  __syncthreads();
  if (tid == 0) {
    const float rs = wsum[0] + wsum[1] + wsum[2] + wsum[3];
#pragma unroll
    for (int b = 0; b < 4; ++b) imp[b * I_ + i] = sqrtf(s[b * I_ + i] * rs);
  }
}

extern "C" void kernel_launch(void* const* d_in, const int* in_sizes, int n_in,
                              void* d_out, int out_size, void* d_ws, size_t ws_size,
                              hipStream_t stream) {
  const float* x = (const float*)d_in[0];   // [4,2048,2048]
  const float* wg = (const float*)d_in[1];  // [5504,2048]
  const float* wu = (const float*)d_in[2];  // [5504,2048]
  const float* wd = (const float*)d_in[3];  // [2048,5504]
  float* out = (float*)d_out;               // [4,2048,2048] then impacts [4,5504]
  float* imp = out + (size_t)M_ * H_;

  char* ws = (char*)d_ws;
  u16* xb = (u16*)(ws);                  // 33,554,432 B
  u16* wcatb = (u16*)(ws + 33554432);    // 45,088,768 B  [11008,2048]
  u16* wdb = (u16*)(ws + 78643200);      // 22,544,384 B
  u16* interb = (u16*)(ws + 101187584);  // 90,177,536 B
  float* s = (float*)(ws + 191365120);   // 88,064 B (total 191,453,184 B)

  cvt_f32_bf16<<<16384, 256, 0, stream>>>(x, xb, (M_ * H_) / 4);
  cvt_wcat<<<22016, 256, 0, stream>>>(wg, wu, wcatb);
  cvt_f32_bf16<<<11008, 256, 0, stream>>>(wd, wdb, (H_ * I_) / 4);
  hipMemsetAsync(s, 0, (size_t)B_ * I_ * sizeof(float), stream);

  // gate+up fused GEMM: [8192,2048] x [11008,2048]^T, 32x43 tiles
  gemm8<1><<<1376, 512, 0, stream>>>(xb, wcatb, 2048, 43, nullptr, interb, s);
  // down GEMM: [8192,5504] x [2048,5504]^T, 32x8 tiles
  gemm8<0><<<256, 512, 0, stream>>>(interb, wdb, 5504, 8, out, nullptr, nullptr);
  rowsq_impacts<<<I_, 256, 0, stream>>>(wu, s, imp);
}

// Round 3
// 765.606 us; speedup vs baseline: 1.7965x; 1.7965x over previous
//
#include <hip/hip_runtime.h>
#include <stdint.h>
#include <stddef.h>

typedef __attribute__((ext_vector_type(8))) short short8;
typedef __attribute__((ext_vector_type(4))) float f32x4;
typedef unsigned short u16;

#define B_ 4
#define S_ 2048
#define H_ 2048
#define I_ 5504
#define M_ 8192  // B*S

__device__ __forceinline__ u16 f2bf(float f) {
  uint32_t u = __float_as_uint(f);
  u += 0x7fff + ((u >> 16) & 1);  // round-to-nearest-even
  return (u16)(u >> 16);
}

#define GLOAD_LDS16(src, dst)                                                            \
  __builtin_amdgcn_global_load_lds((const __attribute__((address_space(1))) void*)(src), \
                                   (__attribute__((address_space(3))) void*)(dst), 16, 0, 0)

// ---- fp32 -> bf16 convert (vectorized) ----
__global__ __launch_bounds__(256) void cvt_f32_bf16(const float* __restrict__ in,
                                                    u16* __restrict__ out, int n4) {
  int i = blockIdx.x * 256 + threadIdx.x;
  if (i < n4) {
    float4 v = ((const float4*)in)[i];
    ushort4 o;
    o.x = f2bf(v.x); o.y = f2bf(v.y); o.z = f2bf(v.z); o.w = f2bf(v.w);
    ((ushort4*)out)[i] = o;
  }
}

// ---- build interleaved W_cat [11008, 2048]: 32-row groups = 16 Wg rows then 16 Wu rows ----
__global__ __launch_bounds__(256) void cvt_wcat(const float* __restrict__ wg,
                                                const float* __restrict__ wu,
                                                u16* __restrict__ wcat) {
  const int i = blockIdx.x * 256 + threadIdx.x;  // float4 index
  const int f = i * 4;
  const int r = f >> 11;  // wcat row (2048 cols per row)
  const int c = f & 2047;
  const int srcrow = (r >> 5) * 16 + (r & 15);
  const float* src = (((r >> 4) & 1) ? wu : wg) + (size_t)srcrow * 2048 + c;
  float4 v = *(const float4*)src;
  ushort4 o;
  o.x = f2bf(v.x); o.y = f2bf(v.y); o.z = f2bf(v.z); o.w = f2bf(v.w);
  *(ushort4*)(wcat + (size_t)r * 2048 + c) = o;
}

// Stage one 16 KiB half-tile (256 rows x 32 k, bf16) into a linear LDS slot.
// LDS dest = wave-uniform base + lane*16 (HW); per-lane global source carries the
// inverse chunk-swizzle (read side XORs the same way) -> bank-conflict-free ds_read.
__device__ __forceinline__ void stage_half(const u16* __restrict__ mbase, int ld, int k0,
                                           char* slot, int tid) {
#pragma unroll
  for (int i = 0; i < 2; ++i) {
    const int f = tid * 16 + i * 8192;                 // lane's byte position in slot
    const int row = f >> 6;                            // 64 B per row (32 bf16)
    const int cl = (f >> 4) & 3;                       // 16B chunk within row
    const int col = k0 + 8 * (cl ^ ((row >> 1) & 3));  // inverse swizzle on source
    GLOAD_LDS16(mbase + (size_t)row * ld + col, slot + ((tid >> 6) * 1024 + i * 8192));
  }
}

#define PH_BAR asm volatile("s_barrier" ::: "memory")
#define WAIT_LGK0                                        \
  {                                                      \
    asm volatile("s_waitcnt lgkmcnt(0)" ::: "memory");   \
    __builtin_amdgcn_sched_barrier(0);                   \
  }

// 16 MFMA: m0-7 x two n-columns, single ks (operands consumed same phase -> low liveness)
#define MM2(av, bx, by, N0, N1)                                                                 \
  {                                                                                             \
    __builtin_amdgcn_s_setprio(1);                                                              \
    _Pragma("unroll") for (int m = 0; m < 8; ++m) {                                             \
      acc[m][N0] = __builtin_amdgcn_mfma_f32_16x16x32_bf16(av[m], bx, acc[m][N0], 0, 0, 0);     \
      acc[m][N1] = __builtin_amdgcn_mfma_f32_16x16x32_bf16(av[m], by, acc[m][N1], 0, 0, 0);     \
    }                                                                                           \
    __builtin_amdgcn_s_setprio(0);                                                              \
  }

// 256x256 tile, BK=64, 8 waves (2M x 4N). 4 phases per K-tile, same-phase operand
// consumption, slot-granular write-behind staging 2 tiles ahead, counted vmcnt(6).
// EPI=0: fp32 C write (down proj). EPI=1: SwiGLU epilogue (gate/up interleaved in B).
template <int EPI>
__global__ __launch_bounds__(512, 1) void gemm8(const u16* __restrict__ A,
                                                const u16* __restrict__ Bm, const int K,
                                                const int NT, float* __restrict__ outf,
                                                u16* __restrict__ inter, float* __restrict__ s) {
  __shared__ __align__(16) char lds_raw[131072 + 512];

  const int nwg = gridDim.x;  // divisible by 8
  const int cpx = nwg >> 3;
  const int swz = (blockIdx.x & 7) * cpx + (blockIdx.x >> 3);
  const int mt = swz / NT;
  const int nt = swz % NT;

  const int tid = threadIdx.x;
  const int lane = tid & 63;
  const int wid = tid >> 6;
  const int wr = wid >> 2;  // 0..1  (M half)
  const int wc = wid & 3;   // 0..3  (N quarter)
  const int l15 = lane & 15;

  if (tid < 128) ((float*)(lds_raw + 131072))[tid] = 0.f;

  // swizzled ds_read offsets: chunk = (lane>>4) ^ ((l15>>1)&3)
  const int chunkx = (l15 >> 1) & 3;
  const int aoff = (wr * 128 + l15) * 64 + (((lane >> 4) ^ chunkx) << 4);
  const int boff = (wc * 64 + l15) * 64 + (((lane >> 4) ^ chunkx) << 4);

  const u16* Abase = A + (size_t)(mt * 256) * K;
  const u16* Bbase = Bm + (size_t)(nt * 256) * K;

// slot q: 0=A_k0 1=A_k1 2=B_k0 3=B_k1 ; buffer = tile&1
#define STG(v, q)                                                   \
  stage_half((q) < 2 ? Abase : Bbase, K, (v) * 64 + ((q) & 1) * 32, \
             lds_raw + (((v) & 1) * 65536 + (q) * 16384), tid)
#define RDA8(dst, c, ks)                                         \
  _Pragma("unroll") for (int m = 0; m < 8; ++m) dst[m] =         \
      *(const short8*)(lds_raw + (c) * 65536 + (ks) * 16384 + aoff + m * 1024);
#define RDB(dst, c, ks, n) \
  dst = *(const short8*)(lds_raw + (c) * 65536 + 32768 + (ks) * 16384 + boff + (n) * 1024);

  f32x4 acc[8][4] = {};
  short8 a[8], a2[8];
  short8 bx, by;

  const int T = K >> 6;  // K-tiles (32 or 86)

  // ---- prologue: tile0 all 4 slots + tile1 {A0,B0,A1}; keep 3 STG in flight
  STG(0, 0); STG(0, 1); STG(0, 2); STG(0, 3);
  STG(1, 0); STG(1, 2); STG(1, 1);
  asm volatile("s_waitcnt vmcnt(6)" ::: "memory");  // tile0's 8 loads landed
  PH_BAR;

#pragma unroll 1
  for (int t = 0; t < T; ++t) {
    const int c = t & 1;
    const bool s1 = (t + 1 < T);
    const bool s2 = (t + 2 < T);
    // P0: read A ks0 + B{n0,n1} ks0; stage B1(t+1) into other buffer (slot dead since t-1 P3)
    RDA8(a, c, 0);
    RDB(bx, c, 0, 0);
    RDB(by, c, 0, 1);
    if (s1) STG(t + 1, 3);
    PH_BAR;
    WAIT_LGK0;
    MM2(a, bx, by, 0, 1);
    PH_BAR;
    // P1: read B{n2,n3} ks0; stage A0(t+2) into current buffer slot0 (dead after P0)
    RDB(bx, c, 0, 2);
    RDB(by, c, 0, 3);
    if (s2) STG(t + 2, 0);
    PH_BAR;
    WAIT_LGK0;
    MM2(a, bx, by, 2, 3);
    PH_BAR;
    // P2: read A ks1 + B{n0,n1} ks1; stage B0(t+2) (dead after P1)
    RDA8(a2, c, 1);
    RDB(bx, c, 1, 0);
    RDB(by, c, 1, 1);
    if (s2) STG(t + 2, 2);
    PH_BAR;
    WAIT_LGK0;
    MM2(a2, bx, by, 0, 1);
    PH_BAR;
    // P3: read B{n2,n3} ks1; stage A1(t+2) (dead after P2); tile-boundary counted vmcnt
    RDB(bx, c, 1, 2);
    RDB(by, c, 1, 3);
    if (s2) STG(t + 2, 1);
    PH_BAR;
    if (s2) {
      asm volatile("s_waitcnt vmcnt(6) lgkmcnt(0)" ::: "memory");  // keep 3 STG in flight
    } else {
      asm volatile("s_waitcnt vmcnt(0) lgkmcnt(0)" ::: "memory");  // tail drain
    }
    __builtin_amdgcn_sched_barrier(0);
    MM2(a2, bx, by, 2, 3);
    PH_BAR;
  }

  // C/D frag mapping: col = lane&15, row = (lane>>4)*4 + j
  const int r0 = mt * 256 + wr * 128 + (lane >> 4) * 4;
  if constexpr (EPI == 0) {
    const int c0 = nt * 256 + wc * 64 + l15;
#pragma unroll
    for (int m = 0; m < 8; ++m)
#pragma unroll
      for (int n = 0; n < 4; ++n)
#pragma unroll
        for (int j = 0; j < 4; ++j)
          outf[(size_t)(r0 + m * 16 + j) * 2048 + (c0 + n * 16)] = acc[m][n][j];
  } else {
    // n pairs (0,1)=(gate,up) cols c0..c0+15 ; (2,3)=(gate,up) cols c0+16..c0+31
    float* s_tile = (float*)(lds_raw + 131072);
    const int c0 = nt * 128 + wc * 32 + l15;
    float sp0 = 0.f, sp1 = 0.f;
#pragma unroll
    for (int m = 0; m < 8; ++m) {
#pragma unroll
      for (int j = 0; j < 4; ++j) {
        {
          const float g = acc[m][0][j], u = acc[m][1][j];
          const float v = (g / (1.f + __expf(-g))) * u;
          sp0 += v * v;
          inter[(size_t)(r0 + m * 16 + j) * I_ + c0] = f2bf(v);
        }
        {
          const float g = acc[m][2][j], u = acc[m][3][j];
          const float v = (g / (1.f + __expf(-g))) * u;
          sp1 += v * v;
          inter[(size_t)(r0 + m * 16 + j) * I_ + (c0 + 16)] = f2bf(v);
        }
      }
    }
    atomicAdd(&s_tile[wc * 32 + l15], sp0);
    atomicAdd(&s_tile[wc * 32 + 16 + l15], sp1);
    __syncthreads();
    if (tid < 128) atomicAdd(&s[(mt >> 3) * I_ + nt * 128 + tid], s_tile[tid]);
  }
#undef STG
#undef RDA8
#undef RDB
}

// ---- row_sq (fp32 w_up) + impacts ----
__global__ __launch_bounds__(256) void rowsq_impacts(const float* __restrict__ wu,
                                                     const float* __restrict__ s,
                                                     float* __restrict__ imp) {
  const int i = blockIdx.x;
  const int tid = threadIdx.x;
  const float4* row = (const float4*)(wu + (size_t)i * H_);
  float acc = 0.f;
#pragma unroll
  for (int t = 0; t < 2; ++t) {
    float4 v = row[tid + t * 256];
    acc += v.x * v.x + v.y * v.y + v.z * v.z + v.w * v.w;
  }
#pragma unroll
  for (int off = 32; off > 0; off >>= 1) acc += __shfl_down(acc, off, 64);
  __shared__ float wsum[4];
  if ((tid & 63) == 0) wsum[tid >> 6] = acc;
  __syncthreads();
  if (tid == 0) {
    const float rs = wsum[0] + wsum[1] + wsum[2] + wsum[3];
#pragma unroll
    for (int b = 0; b < 4; ++b) imp[b * I_ + i] = sqrtf(s[b * I_ + i] * rs);
  }
}

extern "C" void kernel_launch(void* const* d_in, const int* in_sizes, int n_in,
                              void* d_out, int out_size, void* d_ws, size_t ws_size,
                              hipStream_t stream) {
  const float* x = (const float*)d_in[0];   // [4,2048,2048]
  const float* wg = (const float*)d_in[1];  // [5504,2048]
  const float* wu = (const float*)d_in[2];  // [5504,2048]
  const float* wd = (const float*)d_in[3];  // [2048,5504]
  float* out = (float*)d_out;               // [4,2048,2048] then impacts [4,5504]
  float* imp = out + (size_t)M_ * H_;

  char* ws = (char*)d_ws;
  u16* xb = (u16*)(ws);                  // 33,554,432 B
  u16* wcatb = (u16*)(ws + 33554432);    // 45,088,768 B  [11008,2048]
  u16* wdb = (u16*)(ws + 78643200);      // 22,544,384 B
  u16* interb = (u16*)(ws + 101187584);  // 90,177,536 B
  float* s = (float*)(ws + 191365120);   // 88,064 B (total 191,453,184 B)

  cvt_f32_bf16<<<16384, 256, 0, stream>>>(x, xb, (M_ * H_) / 4);
  cvt_wcat<<<22016, 256, 0, stream>>>(wg, wu, wcatb);
  cvt_f32_bf16<<<11008, 256, 0, stream>>>(wd, wdb, (H_ * I_) / 4);
  hipMemsetAsync(s, 0, (size_t)B_ * I_ * sizeof(float), stream);

  // gate+up fused GEMM: [8192,2048] x [11008,2048]^T, 32x43 tiles of 256^2
  gemm8<1><<<1376, 512, 0, stream>>>(xb, wcatb, 2048, 43, nullptr, interb, s);
  // down GEMM: [8192,5504] x [2048,5504]^T, 32x8 tiles of 256^2
  gemm8<0><<<256, 512, 0, stream>>>(interb, wdb, 5504, 8, out, nullptr, nullptr);
  rowsq_impacts<<<I_, 256, 0, stream>>>(wu, s, imp);
}

// Round 4
// 713.220 us; speedup vs baseline: 1.9284x; 1.0735x over previous
//
#include <hip/hip_runtime.h>
#include <stdint.h>
#include <stddef.h>

typedef __attribute__((ext_vector_type(8))) short short8;
typedef __attribute__((ext_vector_type(4))) float f32x4;
typedef unsigned short u16;

#define B_ 4
#define S_ 2048
#define H_ 2048
#define I_ 5504
#define M_ 8192  // B*S

__device__ __forceinline__ u16 f2bf(float f) {
  uint32_t u = __float_as_uint(f);
  u += 0x7fff + ((u >> 16) & 1);  // round-to-nearest-even
  return (u16)(u >> 16);
}

#define GLOAD_LDS16(src, dst)                                                            \
  __builtin_amdgcn_global_load_lds((const __attribute__((address_space(1))) void*)(src), \
                                   (__attribute__((address_space(3))) void*)(dst), 16, 0, 0)

// ---- fp32 -> bf16 convert (vectorized) ----
__global__ __launch_bounds__(256) void cvt_f32_bf16(const float* __restrict__ in,
                                                    u16* __restrict__ out, int n4) {
  int i = blockIdx.x * 256 + threadIdx.x;
  if (i < n4) {
    float4 v = ((const float4*)in)[i];
    ushort4 o;
    o.x = f2bf(v.x); o.y = f2bf(v.y); o.z = f2bf(v.z); o.w = f2bf(v.w);
    ((ushort4*)out)[i] = o;
  }
}

// ---- build interleaved W_cat [11008, 2048]: 32-row groups = 16 Wg rows then 16 Wu rows ----
__global__ __launch_bounds__(256) void cvt_wcat(const float* __restrict__ wg,
                                                const float* __restrict__ wu,
                                                u16* __restrict__ wcat) {
  const int i = blockIdx.x * 256 + threadIdx.x;  // float4 index
  const int f = i * 4;
  const int r = f >> 11;  // wcat row (2048 cols per row)
  const int c = f & 2047;
  const int srcrow = (r >> 5) * 16 + (r & 15);
  const float* src = (((r >> 4) & 1) ? wu : wg) + (size_t)srcrow * 2048 + c;
  float4 v = *(const float4*)src;
  ushort4 o;
  o.x = f2bf(v.x); o.y = f2bf(v.y); o.z = f2bf(v.z); o.w = f2bf(v.w);
  *(ushort4*)(wcat + (size_t)r * 2048 + c) = o;
}

#define WAITLGK0 asm volatile("s_waitcnt lgkmcnt(0)" ::: "memory")
#define PH_BAR asm volatile("s_barrier" ::: "memory")

// 16 MFMA cluster (register-only; free to float across asm barriers — desirable)
#define MM2(av, bx, by, N0, N1)                                                             \
  {                                                                                         \
    __builtin_amdgcn_s_setprio(1);                                                          \
    _Pragma("unroll") for (int m = 0; m < 8; ++m) {                                         \
      acc[m][N0] = __builtin_amdgcn_mfma_f32_16x16x32_bf16(av[m], bx, acc[m][N0], 0, 0, 0); \
      acc[m][N1] = __builtin_amdgcn_mfma_f32_16x16x32_bf16(av[m], by, acc[m][N1], 0, 0, 0); \
    }                                                                                       \
    __builtin_amdgcn_s_setprio(0);                                                          \
  }

// 256x256 tile, BK=64, 8 waves (2M x 4N). 4 phases per K-tile, ONE barrier per phase
// (lgkmcnt(0) precedes it -> stage-after-read hazard needs only 1-barrier separation,
// since every stage target's last read is exactly one phase earlier). MFMA clusters are
// register-only and float across barriers; compiler overlaps them with next-phase reads.
// Counted vmcnt(6) once per K-tile keeps 3 half-tile stages in flight.
// EPI=0: fp32 C write (down proj). EPI=1: SwiGLU epilogue (gate/up interleaved in B).
template <int EPI>
__global__ __launch_bounds__(512, 1) void gemm8(const u16* __restrict__ A,
                                                const u16* __restrict__ Bm, const int K,
                                                const int NT, float* __restrict__ outf,
                                                u16* __restrict__ inter, float* __restrict__ s) {
  __shared__ __align__(16) char lds_raw[131072 + 512];

  const int nwg = gridDim.x;  // divisible by 8
  const int cpx = nwg >> 3;
  const int swz = (blockIdx.x & 7) * cpx + (blockIdx.x >> 3);
  const int mt = swz / NT;
  const int nt = swz % NT;

  const int tid = threadIdx.x;
  const int lane = tid & 63;
  const int wid = tid >> 6;
  const int wr = wid >> 2;  // 0..1  (M half)
  const int wc = wid & 3;   // 0..3  (N quarter)
  const int l15 = lane & 15;

  if (tid < 128) ((float*)(lds_raw + 131072))[tid] = 0.f;

  // swizzled ds_read offsets: chunk = (lane>>4) ^ ((l15>>1)&3)
  const int chunkx = (l15 >> 1) & 3;
  const int aoff = (wr * 128 + l15) * 64 + (((lane >> 4) ^ chunkx) << 4);
  const int boff = (wc * 64 + l15) * 64 + (((lane >> 4) ^ chunkx) << 4);

  const u16* Abase = A + (size_t)(mt * 256) * K;
  const u16* Bbase = Bm + (size_t)(nt * 256) * K;

  // Precomputed stage addressing (per-thread constants; per-call adds only k0).
  // flat byte f = tid*16 + i*8192 ; row = f>>6 ; chunk cl = (f>>4)&3 ;
  // source col = k0 + 8*(cl ^ ((row>>1)&3))  (inverse swizzle on global source)
  int goff[2], loff[2];
#pragma unroll
  for (int i = 0; i < 2; ++i) {
    const int f = tid * 16 + i * 8192;
    const int row = f >> 6;
    const int cl = (f >> 4) & 3;
    goff[i] = row * K + 8 * (cl ^ ((row >> 1) & 3));  // elements
    loff[i] = (tid >> 6) * 1024 + i * 8192;           // bytes within slot
  }

// slot q: 0=A_k0 1=A_k1 2=B_k0 3=B_k1 ; buffer = tile&1
#define STG(v, q)                                                              \
  {                                                                            \
    const u16* _b = ((q) < 2 ? Abase : Bbase) + (v) * 64 + ((q) & 1) * 32;     \
    char* _s = lds_raw + (((v) & 1) * 65536 + (q) * 16384);                    \
    GLOAD_LDS16(_b + goff[0], _s + loff[0]);                                   \
    GLOAD_LDS16(_b + goff[1], _s + loff[1]);                                   \
  }
#define RDA8(dst, c, ks)                                 \
  _Pragma("unroll") for (int m = 0; m < 8; ++m) dst[m] = \
      *(const short8*)(lds_raw + (c) * 65536 + (ks) * 16384 + aoff + m * 1024);
#define RDB(dst, c, ks, n) \
  dst = *(const short8*)(lds_raw + (c) * 65536 + 32768 + (ks) * 16384 + boff + (n) * 1024);

  f32x4 acc[8][4] = {};
  short8 a[8], a2[8];

  const int T = K >> 6;  // K-tiles (32 or 86)

  // ---- prologue: tile0 all 4 slots + tile1 {A0,B0,A1}; 3 slots stay in flight
  STG(0, 0); STG(0, 1); STG(0, 2); STG(0, 3);
  STG(1, 0); STG(1, 2); STG(1, 1);
  asm volatile("s_waitcnt vmcnt(6)" ::: "memory");  // tile0's 8 loads landed
  PH_BAR;

#pragma unroll 1
  for (int t = 0; t < T; ++t) {
    const int c = t & 1;
    const bool s1 = (t + 1 < T);
    const bool s2 = (t + 2 < T);
    short8 b0x, b0y, b1x, b1y, b2x, b2y, b3x, b3y;
    // P0: read A ks0 + B{n0,n1} ks0; stage B1(t+1) (slot last read t-1 P3, 1 bar ago)
    RDA8(a, c, 0);
    RDB(b0x, c, 0, 0);
    RDB(b0y, c, 0, 1);
    if (s1) STG(t + 1, 3);
    WAITLGK0;
    PH_BAR;
    MM2(a, b0x, b0y, 0, 1);
    // P1: read B{n2,n3} ks0; stage A0(t+2) (slot last read this-tile P0, 1 bar ago)
    RDB(b1x, c, 0, 2);
    RDB(b1y, c, 0, 3);
    if (s2) STG(t + 2, 0);
    WAITLGK0;
    PH_BAR;
    MM2(a, b1x, b1y, 2, 3);
    // P2: read A ks1 + B{n0,n1} ks1; stage B0(t+2) (last read P1)
    RDA8(a2, c, 1);
    RDB(b2x, c, 1, 0);
    RDB(b2y, c, 1, 1);
    if (s2) STG(t + 2, 2);
    WAITLGK0;
    PH_BAR;
    MM2(a2, b2x, b2y, 0, 1);
    // P3: read B{n2,n3} ks1; stage A1(t+2) (last read P2); tile-boundary counted vmcnt
    RDB(b3x, c, 1, 2);
    RDB(b3y, c, 1, 3);
    if (s2) STG(t + 2, 1);
    if (s2) {
      asm volatile("s_waitcnt vmcnt(6) lgkmcnt(0)" ::: "memory");  // keep 3 slots in flight
    } else {
      asm volatile("s_waitcnt vmcnt(0) lgkmcnt(0)" ::: "memory");  // tail drain
    }
    PH_BAR;
    MM2(a2, b3x, b3y, 2, 3);
  }

  // C/D frag mapping: col = lane&15, row = (lane>>4)*4 + j
  const int r0 = mt * 256 + wr * 128 + (lane >> 4) * 4;
  if constexpr (EPI == 0) {
    const int c0 = nt * 256 + wc * 64 + l15;
#pragma unroll
    for (int m = 0; m < 8; ++m)
#pragma unroll
      for (int n = 0; n < 4; ++n)
#pragma unroll
        for (int j = 0; j < 4; ++j)
          outf[(size_t)(r0 + m * 16 + j) * 2048 + (c0 + n * 16)] = acc[m][n][j];
  } else {
    // n pairs (0,1)=(gate,up) cols c0..c0+15 ; (2,3)=(gate,up) cols c0+16..c0+31
    float* s_tile = (float*)(lds_raw + 131072);
    const int c0 = nt * 128 + wc * 32 + l15;
    float sp0 = 0.f, sp1 = 0.f;
#pragma unroll
    for (int m = 0; m < 8; ++m) {
#pragma unroll
      for (int j = 0; j < 4; ++j) {
        {
          const float g = acc[m][0][j], u = acc[m][1][j];
          const float v = (g / (1.f + __expf(-g))) * u;
          sp0 += v * v;
          inter[(size_t)(r0 + m * 16 + j) * I_ + c0] = f2bf(v);
        }
        {
          const float g = acc[m][2][j], u = acc[m][3][j];
          const float v = (g / (1.f + __expf(-g))) * u;
          sp1 += v * v;
          inter[(size_t)(r0 + m * 16 + j) * I_ + (c0 + 16)] = f2bf(v);
        }
      }
    }
    atomicAdd(&s_tile[wc * 32 + l15], sp0);
    atomicAdd(&s_tile[wc * 32 + 16 + l15], sp1);
    __syncthreads();
    if (tid < 128) atomicAdd(&s[(mt >> 3) * I_ + nt * 128 + tid], s_tile[tid]);
  }
#undef STG
#undef RDA8
#undef RDB
}

// ---- row_sq (fp32 w_up) + impacts ----
__global__ __launch_bounds__(256) void rowsq_impacts(const float* __restrict__ wu,
                                                     const float* __restrict__ s,
                                                     float* __restrict__ imp) {
  const int i = blockIdx.x;
  const int tid = threadIdx.x;
  const float4* row = (const float4*)(wu + (size_t)i * H_);
  float acc = 0.f;
#pragma unroll
  for (int t = 0; t < 2; ++t) {
    float4 v = row[tid + t * 256];
    acc += v.x * v.x + v.y * v.y + v.z * v.z + v.w * v.w;
  }
#pragma unroll
  for (int off = 32; off > 0; off >>= 1) acc += __shfl_down(acc, off, 64);
  __shared__ float wsum[4];
  if ((tid & 63) == 0) wsum[tid >> 6] = acc;
  __syncthreads();
  if (tid == 0) {
    const float rs = wsum[0] + wsum[1] + wsum[2] + wsum[3];
#pragma unroll
    for (int b = 0; b < 4; ++b) imp[b * I_ + i] = sqrtf(s[b * I_ + i] * rs);
  }
}

extern "C" void kernel_launch(void* const* d_in, const int* in_sizes, int n_in,
                              void* d_out, int out_size, void* d_ws, size_t ws_size,
                              hipStream_t stream) {
  const float* x = (const float*)d_in[0];   // [4,2048,2048]
  const float* wg = (const float*)d_in[1];  // [5504,2048]
  const float* wu = (const float*)d_in[2];  // [5504,2048]
  const float* wd = (const float*)d_in[3];  // [2048,5504]
  float* out = (float*)d_out;               // [4,2048,2048] then impacts [4,5504]
  float* imp = out + (size_t)M_ * H_;

  char* ws = (char*)d_ws;
  u16* xb = (u16*)(ws);                  // 33,554,432 B
  u16* wcatb = (u16*)(ws + 33554432);    // 45,088,768 B  [11008,2048]
  u16* wdb = (u16*)(ws + 78643200);      // 22,544,384 B
  u16* interb = (u16*)(ws + 101187584);  // 90,177,536 B
  float* s = (float*)(ws + 191365120);   // 88,064 B (total 191,453,184 B)

  cvt_f32_bf16<<<16384, 256, 0, stream>>>(x, xb, (M_ * H_) / 4);
  cvt_wcat<<<22016, 256, 0, stream>>>(wg, wu, wcatb);
  cvt_f32_bf16<<<11008, 256, 0, stream>>>(wd, wdb, (H_ * I_) / 4);
  hipMemsetAsync(s, 0, (size_t)B_ * I_ * sizeof(float), stream);

  // gate+up fused GEMM: [8192,2048] x [11008,2048]^T, 32x43 tiles of 256^2
  gemm8<1><<<1376, 512, 0, stream>>>(xb, wcatb, 2048, 43, nullptr, interb, s);
  // down GEMM: [8192,5504] x [2048,5504]^T, 32x8 tiles of 256^2
  gemm8<0><<<256, 512, 0, stream>>>(interb, wdb, 5504, 8, out, nullptr, nullptr);
  rowsq_impacts<<<I_, 256, 0, stream>>>(wu, s, imp);
}